// Round 2
// baseline (781.998 us; speedup 1.0000x reference)
//
#include <hip/hip_runtime.h>

// ---------------------------------------------------------------------------
// CapsNet dynamic routing, fused, fp32 — round 2: no-LDS pass kernel.
//   x: [B=64, I=8192, N=8]   W: [I=8192, J=8, N=8, M=16]   out: [B, J=8, M=16]
//
// Round-1 diagnosis: LDS pipe (32 ds_read_b128 + 12 ds_swizzle per i per
// wave) was ~70% busy while VALU was 30% — staging W through LDS was the
// bottleneck, not compute. W is L2/L3-resident; stream it from global on the
// idle vmem pipe instead.
//
// Thread = (b, j), covers all 16 m. Per i:
//   - load W[i,j,:,:] (128 floats) as 32 x float4 directly from global
//     (8 distinct j-addresses per wave instr, hw-coalesced, L2-hit)
//   - u[m] = sum_n x[b,i,n] * W[i,j,n,m]      (128 FMA)
//   - MODE1: logit = dot_m(v, u) in-thread; softmax over the 8 j-lanes via
//     6 shfl_xor; s_acc[m] += c * u[m]
// No __shared__, no __syncthreads in the pass kernel at all.
// ---------------------------------------------------------------------------

#define BB      64
#define ICAPS   8192
#define NDIM    8
#define JCAPS   8
#define MDIM    16
#define NBLK    256
#define ICHUNK  (ICAPS / NBLK)        // 32
#define S_ELEMS (BB * JCAPS * MDIM)   // 8192 floats per s / vsum / out

// MODE 0: uniform c = 1/8 (softmax of zeros)
// MODE 1: c = softmax_j( dot(vsum[b,j,:], u_hat[b,i,j,:]) )
template <int MODE>
__global__ __launch_bounds__(512, 2) void caps_pass_kernel(
    const float* __restrict__ x, const float* __restrict__ W,
    const float* __restrict__ vsum, float* __restrict__ partial)
{
    const int tid = threadIdx.x;             // 0..511
    const int b   = tid >> 3;                // 0..63
    const int j   = tid & 7;                 // 0..7
    const int i0  = blockIdx.x * ICHUNK;

    float s_acc[MDIM];
    #pragma unroll
    for (int m = 0; m < MDIM; ++m) s_acc[m] = 0.f;

    float vreg[MDIM];
    if (MODE == 1) {
        #pragma unroll
        for (int mc = 0; mc < 4; ++mc) {
            const float4 vv = *(const float4*)&vsum[(b * JCAPS + j) * MDIM + mc * 4];
            vreg[mc * 4 + 0] = vv.x; vreg[mc * 4 + 1] = vv.y;
            vreg[mc * 4 + 2] = vv.z; vreg[mc * 4 + 3] = vv.w;
        }
    }

    const float* xb = x + ((size_t)b * ICAPS + i0) * NDIM;
    const float* Wj = W + (size_t)i0 * 1024 + j * 128;   // W[i0, j, 0, 0]

    #pragma unroll 2
    for (int it = 0; it < ICHUNK; ++it) {
        const float4 xa = *(const float4*)(xb + it * NDIM);
        const float4 xc = *(const float4*)(xb + it * NDIM + 4);
        const float xs[8] = {xa.x, xa.y, xa.z, xa.w, xc.x, xc.y, xc.z, xc.w};

        const float* wrow = Wj + (size_t)it * 1024;

        float u[MDIM];
        #pragma unroll
        for (int m = 0; m < MDIM; ++m) u[m] = 0.f;

        #pragma unroll
        for (int n = 0; n < NDIM; ++n) {
            const float4 w0 = *(const float4*)(wrow + n * MDIM);
            const float4 w1 = *(const float4*)(wrow + n * MDIM + 4);
            const float4 w2 = *(const float4*)(wrow + n * MDIM + 8);
            const float4 w3 = *(const float4*)(wrow + n * MDIM + 12);
            const float xn = xs[n];
            u[0]  += xn * w0.x;  u[1]  += xn * w0.y;  u[2]  += xn * w0.z;  u[3]  += xn * w0.w;
            u[4]  += xn * w1.x;  u[5]  += xn * w1.y;  u[6]  += xn * w1.z;  u[7]  += xn * w1.w;
            u[8]  += xn * w2.x;  u[9]  += xn * w2.y;  u[10] += xn * w2.z;  u[11] += xn * w2.w;
            u[12] += xn * w3.x;  u[13] += xn * w3.y;  u[14] += xn * w3.z;  u[15] += xn * w3.w;
        }

        if (MODE == 0) {
            #pragma unroll
            for (int m = 0; m < MDIM; ++m) s_acc[m] += u[m];
        } else {
            // logit for this (b,i,j), fully in-thread
            float lg = 0.f;
            #pragma unroll
            for (int m = 0; m < MDIM; ++m) lg += u[m] * vreg[m];
            // softmax over the 8 j-lanes (lanes differing in bits 0..2)
            float mx = lg;
            mx = fmaxf(mx, __shfl_xor(mx, 1));
            mx = fmaxf(mx, __shfl_xor(mx, 2));
            mx = fmaxf(mx, __shfl_xor(mx, 4));
            const float e = __expf(lg - mx);
            float den = e;
            den += __shfl_xor(den, 1);
            den += __shfl_xor(den, 2);
            den += __shfl_xor(den, 4);
            const float c = e / den;
            #pragma unroll
            for (int m = 0; m < MDIM; ++m) s_acc[m] += c * u[m];
        }
    }

    // ---- store block-partial s: partial[blk][b][j][m] (wave-contiguous) ----
    const float sc = (MODE == 0) ? 0.125f : 1.0f;
    float* pp = partial + (size_t)blockIdx.x * S_ELEMS + (b * JCAPS + j) * MDIM;
    #pragma unroll
    for (int mc = 0; mc < 4; ++mc) {
        float4 o;
        o.x = s_acc[mc * 4 + 0] * sc; o.y = s_acc[mc * 4 + 1] * sc;
        o.z = s_acc[mc * 4 + 2] * sc; o.w = s_acc[mc * 4 + 3] * sc;
        *(float4*)&pp[mc * 4] = o;
    }
}

// Sum 256 partials -> s[b,j,m]; v = squash(s); FINAL: write d_out, else vsum += v.
template <int FINAL>
__global__ __launch_bounds__(256) void caps_reduce_kernel(
    const float* __restrict__ partial, float* __restrict__ vsum, float* __restrict__ out)
{
    __shared__ float sd[256];
    const int bo  = blockIdx.x;     // 0..255, each block covers 32 outputs
    const int tid = threadIdx.x;
    const int tl  = tid >> 3;       // 0..31 output-within-block
    const int kg  = tid & 7;        // 0..7  slot-group
    const int t   = bo * 32 + tl;   // global output index (= b*128 + j*16 + m)

    float ssum = 0.f;
    const float* p = partial + (size_t)kg * 32 * S_ELEMS + t;
    #pragma unroll
    for (int k = 0; k < 32; ++k) ssum += p[(size_t)k * S_ELEMS];
    sd[tid] = ssum;
    __syncthreads();

    if (tid < 32) {
        const int tt = bo * 32 + tid;
        float s = 0.f;
        #pragma unroll
        for (int q = 0; q < 8; ++q) s += sd[tid * 8 + q];
        // squash: sn over the 16 m's of this (b,j) — lanes grouped by 16
        float sn = s * s;
        sn += __shfl_xor(sn, 1);
        sn += __shfl_xor(sn, 2);
        sn += __shfl_xor(sn, 4);
        sn += __shfl_xor(sn, 8);
        const float v = s * sqrtf(sn) / (1.f + sn);
        if (FINAL) out[tt] = v;
        else       vsum[tt] += v;
    }
}

extern "C" void kernel_launch(void* const* d_in, const int* in_sizes, int n_in,
                              void* d_out, int out_size, void* d_ws, size_t ws_size,
                              hipStream_t stream)
{
    const float* x = (const float*)d_in[0];   // [64, 8192, 8]
    const float* W = (const float*)d_in[1];   // [8192, 8, 8, 16]
    float* out = (float*)d_out;               // [64, 8, 16]

    float* partial = (float*)d_ws;                              // 256 * 8192 floats = 8 MB
    float* vsum    = partial + (size_t)NBLK * S_ELEMS;          // 8192 floats

    // vsum accumulates v_1 + v_2 (ws is poisoned each call -> zero it)
    hipMemsetAsync(vsum, 0, S_ELEMS * sizeof(float), stream);

    // pass 1: c uniform
    caps_pass_kernel<0><<<NBLK, 512, 0, stream>>>(x, W, vsum, partial);
    caps_reduce_kernel<0><<<256, 256, 0, stream>>>(partial, vsum, nullptr);  // vsum = v1
    // pass 2: logits = dot(v1, u_hat)
    caps_pass_kernel<1><<<NBLK, 512, 0, stream>>>(x, W, vsum, partial);
    caps_reduce_kernel<0><<<256, 256, 0, stream>>>(partial, vsum, nullptr);  // vsum = v1+v2
    // pass 3 (final): logits = dot(v1+v2, u_hat), output squash
    caps_pass_kernel<1><<<NBLK, 512, 0, stream>>>(x, W, vsum, partial);
    caps_reduce_kernel<1><<<256, 256, 0, stream>>>(partial, vsum, out);
}

// Round 3
// 343.760 us; speedup vs baseline: 2.2748x; 2.2748x over previous
//
#include <hip/hip_runtime.h>

// ---------------------------------------------------------------------------
// CapsNet dynamic routing, fused — round 3: LDS-traffic-reduced VALU kernel.
//   x: [B=64, I=8192, N=8]   W: [I=8192, J=8, N=8, M=16]   out: [B, J=8, M=16]
//
// R1 post-mortem: LDS pipe-bound (W re-read once per (b,j) lane: 2.1 GB/pass).
// R2 post-mortem: global W = 8x redundant L2 traffic, latency-bound at 3.5% VALU.
// R3: keep round-2's proven (b,j)-lane compute mapping, but:
//   - register-block b x2 (lane = b-pair, j): halves W LDS traffic
//   - W staged in LDS as bf16 (halves again), unpack = 1 inst/value
//   - j-stride padded to 272 B -> each wave W-read hits 8 disjoint bank quads
//   - x staged fp32 with slot = b + (b>>3) swizzle -> conflict-free b128 reads
//   - v (routing vector) kept unpacked in 32 regs/lane, loaded once
// ---------------------------------------------------------------------------

#define BB      64
#define ICAPS   8192
#define NDIM    8
#define JCAPS   8
#define MDIM    16
#define NBLK    512
#define ICHUNK  (ICAPS / NBLK)        // 16 i per block
#define IG      8                     // i per LDS stage
#define S_ELEMS (BB * JCAPS * MDIM)   // 8192 floats

// LDS: W bf16 [ii][j*136 + n*16 + m] (j-stride 136 shorts = 272 B, 16 mod 128)
//      X fp32 float4 slots [(ii*2+nh)*71 + (b + (b>>3))]
struct Smem {
    unsigned short W[IG * 1088];   // 17408 B
    float          X[16 * 71 * 4]; // 18176 B
};                                 // total 35584 B

__device__ __forceinline__ unsigned short f2bf(float f) {
    unsigned int u = __float_as_uint(f);
    u += 0x7FFFu + ((u >> 16) & 1u);          // round-to-nearest-even
    return (unsigned short)(u >> 16);
}
__device__ __forceinline__ float bflo(unsigned int p) { return __uint_as_float(p << 16); }
__device__ __forceinline__ float bfhi(unsigned int p) { return __uint_as_float(p & 0xFFFF0000u); }

// MODE 0: uniform c = 1/8 (softmax of zeros). MODE 1: c = softmax_j(dot(v, u_hat)).
template <int MODE>
__global__ __launch_bounds__(256, 3) void caps_pass_kernel(
    const float* __restrict__ x, const float* __restrict__ W,
    const unsigned short* __restrict__ vb,      // bf16 vsum, [b*128 + j*16 + m]
    float* __restrict__ partial)
{
    __shared__ Smem sm;
    const int tid = threadIdx.x;
    const int j   = tid & 7;
    const int bp  = tid >> 3;          // 0..31
    const int b0  = bp * 2;            // lane owns b0, b0+1

    const float4* __restrict__ W4 = (const float4*)W;
    const float4* __restrict__ X4 = (const float4*)x;

    float s_acc[2][16];
    #pragma unroll
    for (int bi = 0; bi < 2; ++bi)
        #pragma unroll
        for (int m = 0; m < 16; ++m) s_acc[bi][m] = 0.f;

    float vf[2][16];
    if (MODE == 1) {
        #pragma unroll
        for (int bi = 0; bi < 2; ++bi) {
            const uint4* vg = (const uint4*)(vb + (size_t)(b0 + bi) * 128 + j * 16);
            const uint4 va = vg[0], vc = vg[1];
            vf[bi][0]=bflo(va.x); vf[bi][1]=bfhi(va.x); vf[bi][2]=bflo(va.y); vf[bi][3]=bfhi(va.y);
            vf[bi][4]=bflo(va.z); vf[bi][5]=bfhi(va.z); vf[bi][6]=bflo(va.w); vf[bi][7]=bfhi(va.w);
            vf[bi][8]=bflo(vc.x); vf[bi][9]=bfhi(vc.x); vf[bi][10]=bflo(vc.y); vf[bi][11]=bfhi(vc.y);
            vf[bi][12]=bflo(vc.z); vf[bi][13]=bfhi(vc.z); vf[bi][14]=bflo(vc.w); vf[bi][15]=bfhi(vc.w);
        }
    }

    for (int st = 0; st < ICHUNK / IG; ++st) {
        const int i0 = blockIdx.x * ICHUNK + st * IG;
        __syncthreads();   // protect previous stage's LDS reads

        // ---- stage W (8 i x 1024 floats -> bf16): 8 float4 per thread ----
        #pragma unroll
        for (int k = 0; k < 8; ++k) {
            const int f4 = k * 256 + tid;
            const int ii = f4 >> 8, jj = (f4 >> 5) & 7, n = (f4 >> 2) & 7, mq = f4 & 3;
            const float4 g = W4[(size_t)i0 * 256 + f4];
            unsigned short h[4] = {f2bf(g.x), f2bf(g.y), f2bf(g.z), f2bf(g.w)};
            *(uint2*)&sm.W[ii * 1088 + jj * 136 + n * 16 + mq * 4] = *(uint2*)h;
        }
        // ---- stage X (8 i x 64 b x 8 n fp32): 4 float4 per thread ----
        #pragma unroll
        for (int k = 0; k < 4; ++k) {
            const int id = k * 256 + tid;
            const int ii = id >> 7, b = (id >> 1) & 63, nh = id & 1;
            const float4 g = X4[(size_t)b * (ICAPS * 2) + (size_t)(i0 + ii) * 2 + nh];
            const int slot = b + (b >> 3);
            *(float4*)&sm.X[((ii * 2 + nh) * 71 + slot) * 4] = g;
        }
        __syncthreads();

        #pragma unroll 1
        for (int ii = 0; ii < IG; ++ii) {
            // x for my 2 b's
            float xs[2][8];
            #pragma unroll
            for (int bi = 0; bi < 2; ++bi) {
                const int b = b0 + bi, slot = b + (b >> 3);
                const float4 xa = *(const float4*)&sm.X[((ii * 2 + 0) * 71 + slot) * 4];
                const float4 xc = *(const float4*)&sm.X[((ii * 2 + 1) * 71 + slot) * 4];
                xs[bi][0]=xa.x; xs[bi][1]=xa.y; xs[bi][2]=xa.z; xs[bi][3]=xa.w;
                xs[bi][4]=xc.x; xs[bi][5]=xc.y; xs[bi][6]=xc.z; xs[bi][7]=xc.w;
            }

            float u[2][16];
            #pragma unroll
            for (int bi = 0; bi < 2; ++bi)
                #pragma unroll
                for (int m = 0; m < 16; ++m) u[bi][m] = 0.f;

            const unsigned short* wb = &sm.W[ii * 1088 + j * 136];
            #pragma unroll
            for (int n = 0; n < 8; ++n) {
                const uint4 wpa = *(const uint4*)(wb + n * 16);      // m 0..7
                const uint4 wpb = *(const uint4*)(wb + n * 16 + 8);  // m 8..15
                float wf[16];
                wf[0]=bflo(wpa.x); wf[1]=bfhi(wpa.x); wf[2]=bflo(wpa.y); wf[3]=bfhi(wpa.y);
                wf[4]=bflo(wpa.z); wf[5]=bfhi(wpa.z); wf[6]=bflo(wpa.w); wf[7]=bfhi(wpa.w);
                wf[8]=bflo(wpb.x); wf[9]=bfhi(wpb.x); wf[10]=bflo(wpb.y); wf[11]=bfhi(wpb.y);
                wf[12]=bflo(wpb.z); wf[13]=bfhi(wpb.z); wf[14]=bflo(wpb.w); wf[15]=bfhi(wpb.w);
                #pragma unroll
                for (int bi = 0; bi < 2; ++bi) {
                    const float xn = xs[bi][n];
                    #pragma unroll
                    for (int m = 0; m < 16; ++m) u[bi][m] += xn * wf[m];
                }
            }

            if (MODE == 0) {
                #pragma unroll
                for (int bi = 0; bi < 2; ++bi)
                    #pragma unroll
                    for (int m = 0; m < 16; ++m) s_acc[bi][m] += u[bi][m];
            } else {
                float c[2];
                #pragma unroll
                for (int bi = 0; bi < 2; ++bi) {
                    float lg = 0.f;
                    #pragma unroll
                    for (int m = 0; m < 16; ++m) lg += u[bi][m] * vf[bi][m];
                    // softmax over the 8 j-lanes (lane bits 0..2)
                    float mx = lg;
                    mx = fmaxf(mx, __shfl_xor(mx, 1));
                    mx = fmaxf(mx, __shfl_xor(mx, 2));
                    mx = fmaxf(mx, __shfl_xor(mx, 4));
                    const float e = __expf(lg - mx);
                    float den = e;
                    den += __shfl_xor(den, 1);
                    den += __shfl_xor(den, 2);
                    den += __shfl_xor(den, 4);
                    c[bi] = e / den;
                }
                #pragma unroll
                for (int bi = 0; bi < 2; ++bi)
                    #pragma unroll
                    for (int m = 0; m < 16; ++m) s_acc[bi][m] += c[bi] * u[bi][m];
            }
        }
    }

    // ---- store block-partial s ----
    const float sc = (MODE == 0) ? 0.125f : 1.0f;
    #pragma unroll
    for (int bi = 0; bi < 2; ++bi) {
        float* pp = partial + (size_t)blockIdx.x * S_ELEMS + (size_t)(b0 + bi) * 128 + j * 16;
        #pragma unroll
        for (int mq = 0; mq < 4; ++mq) {
            float4 o;
            o.x = s_acc[bi][mq*4+0] * sc; o.y = s_acc[bi][mq*4+1] * sc;
            o.z = s_acc[bi][mq*4+2] * sc; o.w = s_acc[bi][mq*4+3] * sc;
            *(float4*)&pp[mq * 4] = o;
        }
    }
}

// Sum 512 partials -> s; v = squash(s); FINAL: write out, else vsum += v and
// write bf16 copy of the updated vsum for the next pass's logits.
template <int FINAL>
__global__ __launch_bounds__(256) void caps_reduce_kernel(
    const float* __restrict__ partial, float* __restrict__ vsum,
    unsigned short* __restrict__ vb, float* __restrict__ out)
{
    __shared__ float sd[256];
    const int bo  = blockIdx.x;     // 0..255, each block covers 32 outputs
    const int tid = threadIdx.x;
    const int tl  = tid >> 3;       // 0..31 output-within-block
    const int kg  = tid & 7;        // 0..7 slice (64 partials each)
    const int t   = bo * 32 + tl;   // global output index (= b*128 + j*16 + m)

    float ssum = 0.f;
    const float* p = partial + (size_t)kg * 64 * S_ELEMS + t;
    #pragma unroll
    for (int k = 0; k < 64; ++k) ssum += p[(size_t)k * S_ELEMS];
    sd[tid] = ssum;
    __syncthreads();

    if (tid < 32) {
        const int tt = bo * 32 + tid;
        float s = 0.f;
        #pragma unroll
        for (int q = 0; q < 8; ++q) s += sd[tid * 8 + q];
        // squash: sn over the 16 m's of this (b,j) — lanes grouped by 16
        float sn = s * s;
        sn += __shfl_xor(sn, 1);
        sn += __shfl_xor(sn, 2);
        sn += __shfl_xor(sn, 4);
        sn += __shfl_xor(sn, 8);
        const float v = s * sqrtf(sn) / (1.f + sn);
        if (FINAL) {
            out[tt] = v;
        } else {
            const float vn = vsum[tt] + v;
            vsum[tt] = vn;
            vb[tt] = f2bf(vn);
        }
    }
}

extern "C" void kernel_launch(void* const* d_in, const int* in_sizes, int n_in,
                              void* d_out, int out_size, void* d_ws, size_t ws_size,
                              hipStream_t stream)
{
    const float* x = (const float*)d_in[0];   // [64, 8192, 8]
    const float* W = (const float*)d_in[1];   // [8192, 8, 8, 16]
    float* out = (float*)d_out;               // [64, 8, 16]

    float*          partial = (float*)d_ws;                       // 512 * 8192 f = 16.8 MB
    float*          vsum    = partial + (size_t)NBLK * S_ELEMS;   // 8192 f
    unsigned short* vb      = (unsigned short*)(vsum + S_ELEMS);  // 8192 bf16

    hipMemsetAsync(vsum, 0, S_ELEMS * sizeof(float), stream);

    // pass 1: c uniform
    caps_pass_kernel<0><<<NBLK, 256, 0, stream>>>(x, W, nullptr, partial);
    caps_reduce_kernel<0><<<256, 256, 0, stream>>>(partial, vsum, vb, nullptr);  // vsum=v1
    // pass 2: logits = dot(v1, u_hat)
    caps_pass_kernel<1><<<NBLK, 256, 0, stream>>>(x, W, vb, partial);
    caps_reduce_kernel<0><<<256, 256, 0, stream>>>(partial, vsum, vb, nullptr);  // vsum=v1+v2
    // pass 3 (final): logits = dot(v1+v2, u_hat), output squash
    caps_pass_kernel<1><<<NBLK, 256, 0, stream>>>(x, W, vb, partial);
    caps_reduce_kernel<1><<<256, 256, 0, stream>>>(partial, vsum, vb, out);
}

// Round 4
// 252.843 us; speedup vs baseline: 3.0928x; 1.3596x over previous
//
#include <hip/hip_runtime.h>

// ---------------------------------------------------------------------------
// CapsNet dynamic routing, fused — round 4: round-3 structure, spill fixed.
//   x: [B=64, I=8192, N=8]   W: [I=8192, J=8, N=8, M=16]   out: [B, J=8, M=16]
//
// R3 post-mortem: __launch_bounds__(256,3) + fully-unrolled n-loop forced
// VGPR=84 vs ~130 live -> per-iter scratch spills (WRITE_SIZE 143 MB/pass vs
// 16.8 expected). Fixes:
//   - no min-wave cap: let allocator take ~150 VGPRs (3 blocks/CU is plenty)
//   - v kept PACKED bf16 (8 uints/2b), unpacked inline in logit dot (-32 regs)
//   - #pragma unroll 2 on n-loop: caps in-flight W uint4s at 4 (-~40 regs of
//     scheduler lookahead)
// Everything else identical to round 3 (bf16 W in LDS, 2 b/lane, padded
// strides, partial-s + reduce/squash kernels).
// ---------------------------------------------------------------------------

#define BB      64
#define ICAPS   8192
#define NDIM    8
#define JCAPS   8
#define MDIM    16
#define NBLK    512
#define ICHUNK  (ICAPS / NBLK)        // 16 i per block
#define IG      8                     // i per LDS stage
#define S_ELEMS (BB * JCAPS * MDIM)   // 8192 floats

// LDS: W bf16 [ii][j*136 + n*16 + m] (j-stride 136 shorts = 272 B)
//      X fp32 float4 slots [(ii*2+nh)*71 + (b + (b>>3))]
struct Smem {
    unsigned short W[IG * 1088];   // 17408 B
    float          X[16 * 71 * 4]; // 18176 B
};                                 // total 35584 B

__device__ __forceinline__ unsigned short f2bf(float f) {
    unsigned int u = __float_as_uint(f);
    u += 0x7FFFu + ((u >> 16) & 1u);          // round-to-nearest-even
    return (unsigned short)(u >> 16);
}
__device__ __forceinline__ float bflo(unsigned int p) { return __uint_as_float(p << 16); }
__device__ __forceinline__ float bfhi(unsigned int p) { return __uint_as_float(p & 0xFFFF0000u); }

// MODE 0: uniform c = 1/8 (softmax of zeros). MODE 1: c = softmax_j(dot(v, u_hat)).
template <int MODE>
__global__ __launch_bounds__(256) void caps_pass_kernel(
    const float* __restrict__ x, const float* __restrict__ W,
    const unsigned short* __restrict__ vb,      // bf16 vsum, [b*128 + j*16 + m]
    float* __restrict__ partial)
{
    __shared__ Smem sm;
    const int tid = threadIdx.x;
    const int j   = tid & 7;
    const int bp  = tid >> 3;          // 0..31
    const int b0  = bp * 2;            // lane owns b0, b0+1

    const float4* __restrict__ W4 = (const float4*)W;
    const float4* __restrict__ X4 = (const float4*)x;

    float s_acc[2][16];
    #pragma unroll
    for (int bi = 0; bi < 2; ++bi)
        #pragma unroll
        for (int m = 0; m < 16; ++m) s_acc[bi][m] = 0.f;

    // v kept PACKED (bf16 pairs): vpk[bi][p] covers m = 2p, 2p+1
    unsigned int vpk[2][8];
    if (MODE == 1) {
        #pragma unroll
        for (int bi = 0; bi < 2; ++bi) {
            const uint4* vg = (const uint4*)(vb + (size_t)(b0 + bi) * 128 + j * 16);
            const uint4 va = vg[0], vc = vg[1];
            vpk[bi][0] = va.x; vpk[bi][1] = va.y; vpk[bi][2] = va.z; vpk[bi][3] = va.w;
            vpk[bi][4] = vc.x; vpk[bi][5] = vc.y; vpk[bi][6] = vc.z; vpk[bi][7] = vc.w;
        }
    }

    for (int st = 0; st < ICHUNK / IG; ++st) {
        const int i0 = blockIdx.x * ICHUNK + st * IG;
        __syncthreads();   // protect previous stage's LDS reads

        // ---- stage W (8 i x 1024 floats -> bf16): 8 float4 per thread ----
        #pragma unroll
        for (int k = 0; k < 8; ++k) {
            const int f4 = k * 256 + tid;
            const int ii = f4 >> 8, jj = (f4 >> 5) & 7, n = (f4 >> 2) & 7, mq = f4 & 3;
            const float4 g = W4[(size_t)i0 * 256 + f4];
            unsigned short h[4] = {f2bf(g.x), f2bf(g.y), f2bf(g.z), f2bf(g.w)};
            *(uint2*)&sm.W[ii * 1088 + jj * 136 + n * 16 + mq * 4] = *(uint2*)h;
        }
        // ---- stage X (8 i x 64 b x 8 n fp32): 4 float4 per thread ----
        #pragma unroll
        for (int k = 0; k < 4; ++k) {
            const int id = k * 256 + tid;
            const int ii = id >> 7, b = (id >> 1) & 63, nh = id & 1;
            const float4 g = X4[(size_t)b * (ICAPS * 2) + (size_t)(i0 + ii) * 2 + nh];
            const int slot = b + (b >> 3);
            *(float4*)&sm.X[((ii * 2 + nh) * 71 + slot) * 4] = g;
        }
        __syncthreads();

        #pragma unroll 1
        for (int ii = 0; ii < IG; ++ii) {
            // x for my 2 b's
            float xs[2][8];
            #pragma unroll
            for (int bi = 0; bi < 2; ++bi) {
                const int b = b0 + bi, slot = b + (b >> 3);
                const float4 xa = *(const float4*)&sm.X[((ii * 2 + 0) * 71 + slot) * 4];
                const float4 xc = *(const float4*)&sm.X[((ii * 2 + 1) * 71 + slot) * 4];
                xs[bi][0]=xa.x; xs[bi][1]=xa.y; xs[bi][2]=xa.z; xs[bi][3]=xa.w;
                xs[bi][4]=xc.x; xs[bi][5]=xc.y; xs[bi][6]=xc.z; xs[bi][7]=xc.w;
            }

            float u[2][16];
            #pragma unroll
            for (int bi = 0; bi < 2; ++bi)
                #pragma unroll
                for (int m = 0; m < 16; ++m) u[bi][m] = 0.f;

            const unsigned short* wb = &sm.W[ii * 1088 + j * 136];
            // unroll 2: cap in-flight W loads (4 uint4) -> no register blowup
            #pragma unroll 2
            for (int n = 0; n < 8; ++n) {
                const uint4 wpa = *(const uint4*)(wb + n * 16);      // m 0..7
                const uint4 wpb = *(const uint4*)(wb + n * 16 + 8);  // m 8..15
                float wf[16];
                wf[0]=bflo(wpa.x); wf[1]=bfhi(wpa.x); wf[2]=bflo(wpa.y); wf[3]=bfhi(wpa.y);
                wf[4]=bflo(wpa.z); wf[5]=bfhi(wpa.z); wf[6]=bflo(wpa.w); wf[7]=bfhi(wpa.w);
                wf[8]=bflo(wpb.x); wf[9]=bfhi(wpb.x); wf[10]=bflo(wpb.y); wf[11]=bfhi(wpb.y);
                wf[12]=bflo(wpb.z); wf[13]=bfhi(wpb.z); wf[14]=bflo(wpb.w); wf[15]=bfhi(wpb.w);
                #pragma unroll
                for (int bi = 0; bi < 2; ++bi) {
                    const float xn = xs[bi][n];
                    #pragma unroll
                    for (int m = 0; m < 16; ++m) u[bi][m] += xn * wf[m];
                }
            }

            if (MODE == 0) {
                #pragma unroll
                for (int bi = 0; bi < 2; ++bi)
                    #pragma unroll
                    for (int m = 0; m < 16; ++m) s_acc[bi][m] += u[bi][m];
            } else {
                float c[2];
                #pragma unroll
                for (int bi = 0; bi < 2; ++bi) {
                    float lg = 0.f;
                    #pragma unroll
                    for (int p = 0; p < 8; ++p) {
                        const unsigned int pk = vpk[bi][p];
                        lg += u[bi][2 * p]     * bflo(pk);
                        lg += u[bi][2 * p + 1] * bfhi(pk);
                    }
                    // softmax over the 8 j-lanes (lane bits 0..2)
                    float mx = lg;
                    mx = fmaxf(mx, __shfl_xor(mx, 1));
                    mx = fmaxf(mx, __shfl_xor(mx, 2));
                    mx = fmaxf(mx, __shfl_xor(mx, 4));
                    const float e = __expf(lg - mx);
                    float den = e;
                    den += __shfl_xor(den, 1);
                    den += __shfl_xor(den, 2);
                    den += __shfl_xor(den, 4);
                    c[bi] = e / den;
                }
                #pragma unroll
                for (int bi = 0; bi < 2; ++bi)
                    #pragma unroll
                    for (int m = 0; m < 16; ++m) s_acc[bi][m] += c[bi] * u[bi][m];
            }
        }
    }

    // ---- store block-partial s ----
    const float sc = (MODE == 0) ? 0.125f : 1.0f;
    #pragma unroll
    for (int bi = 0; bi < 2; ++bi) {
        float* pp = partial + (size_t)blockIdx.x * S_ELEMS + (size_t)(b0 + bi) * 128 + j * 16;
        #pragma unroll
        for (int mq = 0; mq < 4; ++mq) {
            float4 o;
            o.x = s_acc[bi][mq*4+0] * sc; o.y = s_acc[bi][mq*4+1] * sc;
            o.z = s_acc[bi][mq*4+2] * sc; o.w = s_acc[bi][mq*4+3] * sc;
            *(float4*)&pp[mq * 4] = o;
        }
    }
}

// Sum 512 partials -> s; v = squash(s); FINAL: write out, else vsum += v and
// write bf16 copy of the updated vsum for the next pass's logits.
template <int FINAL>
__global__ __launch_bounds__(256) void caps_reduce_kernel(
    const float* __restrict__ partial, float* __restrict__ vsum,
    unsigned short* __restrict__ vb, float* __restrict__ out)
{
    __shared__ float sd[256];
    const int bo  = blockIdx.x;     // 0..255, each block covers 32 outputs
    const int tid = threadIdx.x;
    const int tl  = tid >> 3;       // 0..31 output-within-block
    const int kg  = tid & 7;        // 0..7 slice (64 partials each)
    const int t   = bo * 32 + tl;   // global output index (= b*128 + j*16 + m)

    float ssum = 0.f;
    const float* p = partial + (size_t)kg * 64 * S_ELEMS + t;
    #pragma unroll
    for (int k = 0; k < 64; ++k) ssum += p[(size_t)k * S_ELEMS];
    sd[tid] = ssum;
    __syncthreads();

    if (tid < 32) {
        const int tt = bo * 32 + tid;
        float s = 0.f;
        #pragma unroll
        for (int q = 0; q < 8; ++q) s += sd[tid * 8 + q];
        // squash: sn over the 16 m's of this (b,j) — lanes grouped by 16
        float sn = s * s;
        sn += __shfl_xor(sn, 1);
        sn += __shfl_xor(sn, 2);
        sn += __shfl_xor(sn, 4);
        sn += __shfl_xor(sn, 8);
        const float v = s * sqrtf(sn) / (1.f + sn);
        if (FINAL) {
            out[tt] = v;
        } else {
            const float vn = vsum[tt] + v;
            vsum[tt] = vn;
            vb[tt] = f2bf(vn);
        }
    }
}

extern "C" void kernel_launch(void* const* d_in, const int* in_sizes, int n_in,
                              void* d_out, int out_size, void* d_ws, size_t ws_size,
                              hipStream_t stream)
{
    const float* x = (const float*)d_in[0];   // [64, 8192, 8]
    const float* W = (const float*)d_in[1];   // [8192, 8, 8, 16]
    float* out = (float*)d_out;               // [64, 8, 16]

    float*          partial = (float*)d_ws;                       // 512 * 8192 f = 16.8 MB
    float*          vsum    = partial + (size_t)NBLK * S_ELEMS;   // 8192 f
    unsigned short* vb      = (unsigned short*)(vsum + S_ELEMS);  // 8192 bf16

    hipMemsetAsync(vsum, 0, S_ELEMS * sizeof(float), stream);

    // pass 1: c uniform
    caps_pass_kernel<0><<<NBLK, 256, 0, stream>>>(x, W, nullptr, partial);
    caps_reduce_kernel<0><<<256, 256, 0, stream>>>(partial, vsum, vb, nullptr);  // vsum=v1
    // pass 2: logits = dot(v1, u_hat)
    caps_pass_kernel<1><<<NBLK, 256, 0, stream>>>(x, W, vb, partial);
    caps_reduce_kernel<0><<<256, 256, 0, stream>>>(partial, vsum, vb, nullptr);  // vsum=v1+v2
    // pass 3 (final): logits = dot(v1+v2, u_hat), output squash
    caps_pass_kernel<1><<<NBLK, 256, 0, stream>>>(x, W, vb, partial);
    caps_reduce_kernel<1><<<256, 256, 0, stream>>>(partial, vsum, vb, out);
}